// Round 1
// baseline (488.123 us; speedup 1.0000x reference)
//
#include <hip/hip_runtime.h>

#define TB 8
#define TC 64
#define TT 300
#define TDD 161
#define TH 128
#define TO 64
#define TN (TB * TDD)          // 1288 sequences
#define TWOH 256
#define NKS 6                  // (C + H) / 32 = 192/32
#define TILE 16
#define NBLK ((TN + TILE - 1) / TILE)   // 81
#define ODCH (TO * TDD)        // 10304 channels
#define TOTAL (TB * TO * TT * TDD)      // 24729600

typedef __attribute__((ext_vector_type(8))) short bf16x8;
typedef __attribute__((ext_vector_type(4))) float f32x4;

__device__ __forceinline__ ushort f2bf(float f) {
  union { float f; unsigned u; } v; v.f = f;
  return (ushort)((v.u + 0x7fffu + ((v.u >> 16) & 1u)) >> 16);  // RNE
}

// assumed k-mapping for 16x16x32 bf16 A/B fragments (two x16 halves stacked).
// NOTE: any error here is a pure k-permutation applied to BOTH A and B -> cancels.
__device__ __forceinline__ int kmap(int e, int q) {
  return ((e < 4) ? 0 : 16) + q * 4 + (e & 3);
}

// ldsA fragment-order index for element (row, k_global)
__device__ __forceinline__ int aidx(int row, int kg) {
  int ks = kg >> 5, k32 = kg & 31;
  int half = k32 >> 4, qq = (k32 >> 2) & 3, em = k32 & 3;
  return ((ks * 4 + qq) * 16 + row) * 8 + half * 4 + em;
}

__global__ __launch_bounds__(512) void gru_kernel(
    const float* __restrict__ x, const int* __restrict__ lengths,
    const float* __restrict__ Wx, const float* __restrict__ Wh,
    const float* __restrict__ bias, const float* __restrict__ Wo,
    const float* __restrict__ bo, float* __restrict__ yout,
    float* __restrict__ ws)
{
  __shared__ __align__(16) ushort ldsA[NKS * 4 * 16 * 8];  // A frags: [x_t | h], bf16
  __shared__ __align__(16) float lds_hp[16 * 256];         // gate pre-activations
  __shared__ __align__(16) float lds_h[16 * 128];          // fp32 h state
  __shared__ int s_b[TILE], s_d[TILE], s_len[TILE], s_ok[TILE];

  const int tid = threadIdx.x;
  const int w = tid >> 6, l = tid & 63, q = l >> 4, r = l & 15;

  if (tid < TILE) {
    int n = blockIdx.x * TILE + tid;
    int ok = (n < TN) ? 1 : 0;
    int b = ok ? (n / TDD) : 0;
    int d = ok ? (n - b * TDD) : 0;
    s_b[tid] = b; s_d[tid] = d; s_ok[tid] = ok;
    s_len[tid] = ok ? lengths[b] : -1;
  }
  for (int i = tid; i < 16 * 128; i += 512) lds_h[i] = 0.0f;
  for (int i = tid; i < 4 * 4 * 16 * 8; i += 512) ldsA[2 * 4 * 16 * 8 + i] = 0; // h part = 0
  __syncthreads();

  // ---- x loader setup: thread -> (c = tid/8, two nn = (tid%8)*2 + {0,1})
  const int xc = tid >> 3;
  const int xn0 = (tid & 7) * 2;
  int xok[2], xbase[2], xa[2];
  #pragma unroll
  for (int j = 0; j < 2; j++) {
    int nn = xn0 + j;
    xok[j] = s_ok[nn];
    xbase[j] = (s_b[nn] * TC + xc) * (TT * TDD) + s_d[nn];
    xa[j] = aidx(nn, xc);
  }
  // x(t=0) into ldsA
  #pragma unroll
  for (int j = 0; j < 2; j++) {
    float v = xok[j] ? x[xbase[j]] : 0.0f;
    ldsA[xa[j]] = f2bf(v);
  }

  // ---- weight B-fragments, loaded ONCE into registers
  bf16x8 wf[2][NKS];   // wave owns j-tiles {2w, 2w+1}: cols [32w, 32w+32)
  #pragma unroll
  for (int jj = 0; jj < 2; jj++) {
    int col = (w * 2 + jj) * 16 + r;
    #pragma unroll
    for (int ks = 0; ks < NKS; ks++) {
      bf16x8 f;
      #pragma unroll
      for (int e = 0; e < 8; e++) {
        int kg = ks * 32 + kmap(e, q);
        float v = (kg < TC) ? Wx[kg * TWOH + col] : Wh[(kg - TC) * TWOH + col];
        f[e] = (short)f2bf(v);
      }
      wf[jj][ks] = f;
    }
  }
  bf16x8 wo[4];
  float bo_v = 0.0f;
  float ysum[4] = {0, 0, 0, 0}, ysq[4] = {0, 0, 0, 0};
  int ybase[4], ylen[4], yok2[4], yd[4];
  if (w < 4) {  // waves 0..3 own output o-tile = w
    int o = w * 16 + r;
    #pragma unroll
    for (int ks = 0; ks < 4; ks++) {
      bf16x8 f;
      #pragma unroll
      for (int e = 0; e < 8; e++)
        f[e] = (short)f2bf(Wo[(ks * 32 + kmap(e, q)) * TO + o]);
      wo[ks] = f;
    }
    bo_v = bo[o];
    #pragma unroll
    for (int i = 0; i < 4; i++) {
      int nn = q * 4 + i;
      yok2[i] = s_ok[nn];
      ylen[i] = s_len[nn];
      yd[i] = s_d[nn];
      ybase[i] = (s_b[nn] * TO + o) * (TT * TDD) + s_d[nn];
    }
  }
  // ---- gates setup: thread -> (nn = tid/32, k0 = (tid%32)*4)
  const int gnn = tid >> 5;
  const int gk = (tid & 31) * 4;
  const f32x4 bz4 = *(const f32x4*)&bias[gk];
  const f32x4 bc4 = *(const f32x4*)&bias[TH + gk];
  const int ga = aidx(gnn, TC + gk);
  __syncthreads();

  for (int t = 0; t < TT; t++) {
    // prefetch x(t+1) early (hides HBM latency under MFMA phase)
    float px0 = 0.0f, px1 = 0.0f;
    if (t + 1 < TT) {
      px0 = xok[0] ? x[xbase[0] + (t + 1) * TDD] : 0.0f;
      px1 = xok[1] ? x[xbase[1] + (t + 1) * TDD] : 0.0f;
    }
    // phase 1: hp = [x_t | h_{t-1}] @ [[Wx],[Wh]]
    bf16x8 af[NKS];
    #pragma unroll
    for (int ks = 0; ks < NKS; ks++)
      af[ks] = *(const bf16x8*)&ldsA[((ks * 4 + q) * 16 + r) * 8];
    f32x4 acc0 = {0, 0, 0, 0}, acc1 = {0, 0, 0, 0};
    #pragma unroll
    for (int ks = 0; ks < NKS; ks++) {
      acc0 = __builtin_amdgcn_mfma_f32_16x16x32_bf16(af[ks], wf[0][ks], acc0, 0, 0, 0);
      acc1 = __builtin_amdgcn_mfma_f32_16x16x32_bf16(af[ks], wf[1][ks], acc1, 0, 0, 0);
    }
    // phase 2: acc -> lds_hp (C layout: col = lane&15, row = (lane>>4)*4+i)
    {
      int j0 = w * 32 + r;
      #pragma unroll
      for (int i = 0; i < 4; i++) {
        int nn = q * 4 + i;
        lds_hp[nn * 256 + j0] = acc0[i];
        lds_hp[nn * 256 + 16 + j0] = acc1[i];
      }
    }
    __syncthreads();
    // phase 3: gates (all 512 threads, 4 hidden units each)
    {
      f32x4 zi = *(const f32x4*)&lds_hp[gnn * 256 + gk];
      f32x4 ci = *(const f32x4*)&lds_hp[gnn * 256 + TH + gk];
      f32x4 ho = *(const f32x4*)&lds_h[gnn * TH + gk];
      f32x4 hn;
      ushort hb[4];
      #pragma unroll
      for (int i = 0; i < 4; i++) {
        float zv = 1.0f / (1.0f + __expf(-(zi[i] + bz4[i])));
        float cv = 1.0f - 2.0f / (__expf(2.0f * (ci[i] + bc4[i])) + 1.0f);
        float h = zv * ho[i] + (1.0f - zv) * cv;
        hn[i] = h; hb[i] = f2bf(h);
      }
      *(f32x4*)&lds_h[gnn * TH + gk] = hn;
      unsigned lo = (unsigned)hb[0] | ((unsigned)hb[1] << 16);
      unsigned hi = (unsigned)hb[2] | ((unsigned)hb[3] << 16);
      uint2 pk; pk.x = lo; pk.y = hi;
      *(uint2*)&ldsA[ga] = pk;              // h_t -> A frags (bf16)
      if (t + 1 < TT) {                      // x_{t+1} -> A frags
        ldsA[xa[0]] = f2bf(px0);
        ldsA[xa[1]] = f2bf(px1);
      }
    }
    __syncthreads();
    // phase 4: y_t = h_t @ Wo + bo (waves 0..3), masked store + stats
    if (w < 4) {
      bf16x8 ah[4];
      #pragma unroll
      for (int ks = 0; ks < 4; ks++)
        ah[ks] = *(const bf16x8*)&ldsA[(((ks + 2) * 4 + q) * 16 + r) * 8];
      f32x4 ya = {bo_v, bo_v, bo_v, bo_v};
      #pragma unroll
      for (int ks = 0; ks < 4; ks++)
        ya = __builtin_amdgcn_mfma_f32_16x16x32_bf16(ah[ks], wo[ks], ya, 0, 0, 0);
      #pragma unroll
      for (int i = 0; i < 4; i++) {
        if (yok2[i] && t < ylen[i]) {
          float v = ya[i];
          yout[ybase[i] + t * TDD] = v;
          ysum[i] += v; ysq[i] += v * v;
        }
      }
    }
  }
  // per-channel masked sums -> workspace
  if (w < 4) {
    int o = w * 16 + r;
    #pragma unroll
    for (int i = 0; i < 4; i++) {
      if (yok2[i]) {
        atomicAdd(&ws[o * TDD + yd[i]], ysum[i]);
        atomicAdd(&ws[ODCH + o * TDD + yd[i]], ysq[i]);
      }
    }
  }
}

__global__ __launch_bounds__(256) void norm_kernel(
    const int* __restrict__ lengths, const float* __restrict__ gamma,
    const float* __restrict__ beta, const float* __restrict__ ws,
    float* __restrict__ out)
{
  __shared__ float s_cnt;
  if (threadIdx.x == 0) {
    int c = 0;
    #pragma unroll
    for (int b = 0; b < TB; b++) c += lengths[b];
    s_cnt = (float)c;
  }
  __syncthreads();
  int idx = blockIdx.x * 256 + threadIdx.x;   // TOTAL is an exact multiple of 256
  int d = idx % TDD;
  int rem = idx / TDD;
  int t = rem % TT;
  rem /= TT;
  int o = rem & 63;
  int b = rem >> 6;
  float res = 0.0f;
  if (t < lengths[b]) {
    int ch = o * TDD + d;
    float inv = 1.0f / s_cnt;
    float mean = ws[ch] * inv;
    float var = ws[ODCH + ch] * inv - mean * mean;
    res = (out[idx] - mean) * rsqrtf(var + 1e-5f) * gamma[ch] + beta[ch];
  }
  out[idx] = res;   // writes 0 at masked frames -> covers poison
}

extern "C" void kernel_launch(void* const* d_in, const int* in_sizes, int n_in,
                              void* d_out, int out_size, void* d_ws, size_t ws_size,
                              hipStream_t stream)
{
  const float* x       = (const float*)d_in[0];
  const int*   lengths = (const int*)d_in[1];
  const float* Wx      = (const float*)d_in[2];
  const float* Wh      = (const float*)d_in[3];
  const float* bias    = (const float*)d_in[4];
  const float* Wo      = (const float*)d_in[5];
  const float* bo      = (const float*)d_in[6];
  const float* gamma   = (const float*)d_in[7];
  const float* beta    = (const float*)d_in[8];
  float* out = (float*)d_out;
  float* ws  = (float*)d_ws;

  hipMemsetAsync(ws, 0, 2 * ODCH * sizeof(float), stream);
  hipLaunchKernelGGL(gru_kernel, dim3(NBLK), dim3(512), 0, stream,
                     x, lengths, Wx, Wh, bias, Wo, bo, out, ws);
  hipLaunchKernelGGL(norm_kernel, dim3(TOTAL / 256), dim3(256), 0, stream,
                     lengths, gamma, beta, ws, out);
}

// Round 2
// 295.311 us; speedup vs baseline: 1.6529x; 1.6529x over previous
//
#include <hip/hip_runtime.h>

#define TB 8
#define TC 64
#define TT 300
#define TDD 161
#define TH 128
#define TO 64
#define TN (TB * TDD)          // 1288 sequences
#define TWOH 256
#define NKS 6                  // (C + H) / 32 = 192/32
#define TILE 16
#define NBLK ((TN + TILE - 1) / TILE)   // 81
#define ODCH (TO * TDD)        // 10304 channels
#define TOTAL (TB * TO * TT * TDD)      // 24729600
#define AFRAG (NKS * 4 * 16 * 8)        // 3072 ushorts per A-frag buffer

typedef __attribute__((ext_vector_type(8))) short bf16x8;
typedef __attribute__((ext_vector_type(4))) float f32x4;

__device__ __forceinline__ ushort f2bf(float f) {
  union { float f; unsigned u; } v; v.f = f;
  return (ushort)((v.u + 0x7fffu + ((v.u >> 16) & 1u)) >> 16);  // RNE
}

// k-mapping inside a 16x16x32 fragment; identical convention for A and B so
// any permutation error cancels in the contraction (verified in R1).
__device__ __forceinline__ int kmap(int e, int q) {
  return ((e < 4) ? 0 : 16) + q * 4 + (e & 3);
}

// Swizzled ushort index of element (row, kg) in the A-frag buffer.
// Block index B = (ks*4+qq)*16 + row, swizzled row^qq: bijective within each
// 16-row group; readers use the same XOR (they have q==qq), keeps b128 reads
// conflict-free and spreads the scattered h-writes over 4x more banks.
__device__ __forceinline__ int aidx_sw(int row, int kg) {
  int ks = kg >> 5, k32 = kg & 31;
  int half = k32 >> 4, qq = (k32 >> 2) & 3, em = k32 & 3;
  int B = (ks * 4 + qq) * 16 + (row ^ qq);
  return B * 8 + half * 4 + em;
}

__global__ __launch_bounds__(512) void gru_kernel(
    const float* __restrict__ x, const int* __restrict__ lengths,
    const float* __restrict__ Wx, const float* __restrict__ Wh,
    const float* __restrict__ bias, const float* __restrict__ Wo,
    const float* __restrict__ bo, float* __restrict__ yout,
    float* __restrict__ ws)
{
  __shared__ __align__(16) ushort ldsA[2][AFRAG];  // double-buffered [x_t | h] frags
  __shared__ int s_b[TILE], s_d[TILE], s_len[TILE], s_ok[TILE];

  const int tid = threadIdx.x;
  const int w = tid >> 6, l = tid & 63, q = l >> 4, r = l & 15;

  if (tid < TILE) {
    int n = blockIdx.x * TILE + tid;
    int ok = (n < TN) ? 1 : 0;
    int b = ok ? (n / TDD) : 0;
    int d = ok ? (n - b * TDD) : 0;
    s_b[tid] = b; s_d[tid] = d; s_ok[tid] = ok;
    s_len[tid] = ok ? lengths[b] : -1;
  }
  // zero the h-part (kg >= 64 -> ushort idx >= 1024) of buffer 0 (h_{-1} = 0)
  for (int i = tid; i < AFRAG - 1024; i += 512) ldsA[0][1024 + i] = 0;
  __syncthreads();

  // ---- x loader mapping: thread -> (c = tid/8, nn = (tid%8)*2 + {0,1})
  const int xc = tid >> 3;
  const int xn0 = (tid & 7) * 2;
  int xok[2], xbase[2], xa[2];
  #pragma unroll
  for (int j = 0; j < 2; j++) {
    int nn = xn0 + j;
    xok[j] = s_ok[nn];
    xbase[j] = (s_b[nn] * TC + xc) * (TT * TDD) + s_d[nn];
    xa[j] = aidx_sw(nn, xc);
  }
  // x(0) into buffer 0
  #pragma unroll
  for (int j = 0; j < 2; j++) {
    float v = xok[j] ? x[xbase[j]] : 0.0f;
    ldsA[0][xa[j]] = f2bf(v);
  }
  // x prefetch pipeline, distance 3: wx = x(t+1) (ready to stage), sx = x(t+2)
  float wx0 = xok[0] ? x[xbase[0] + 1 * TDD] : 0.0f;
  float wx1 = xok[1] ? x[xbase[1] + 1 * TDD] : 0.0f;
  float sx0 = xok[0] ? x[xbase[0] + 2 * TDD] : 0.0f;
  float sx1 = xok[1] ? x[xbase[1] + 2 * TDD] : 0.0f;

  // ---- weight B-fragments (registers, loaded once)
  // wave w owns z-cols [16w,16w+16) (jj=0) and c-cols [128+16w,...) (jj=1):
  // z and c pre-activations for the SAME unit land in the SAME lane.
  bf16x8 wf[2][NKS];
  const int ucol = w * 16 + r;       // hidden unit this lane owns
  #pragma unroll
  for (int jj = 0; jj < 2; jj++) {
    int col = jj * TH + ucol;
    #pragma unroll
    for (int ks = 0; ks < NKS; ks++) {
      bf16x8 f;
      #pragma unroll
      for (int e = 0; e < 8; e++) {
        int kg = ks * 32 + kmap(e, q);
        float v = (kg < TC) ? Wx[kg * TWOH + col] : Wh[(kg - TC) * TWOH + col];
        f[e] = (short)f2bf(v);
      }
      wf[jj][ks] = f;
    }
  }
  const float bz = bias[ucol];
  const float bc = bias[TH + ucol];

  // per-lane row info (rows nn = q*4+i for both gates and y-store)
  int llen[4], lok[4], ld_[4];
  #pragma unroll
  for (int i = 0; i < 4; i++) {
    int nn = q * 4 + i;
    llen[i] = s_len[nn]; lok[i] = s_ok[nn]; ld_[i] = s_d[nn];
  }
  // h-state in registers + precomputed swizzled write indices
  float hreg[4] = {0, 0, 0, 0};
  int hwi[4];
  #pragma unroll
  for (int i = 0; i < 4; i++) hwi[i] = aidx_sw(q * 4 + i, TC + ucol);

  // ---- y projection setup (waves 0..3 own o-tile w)
  bf16x8 wo[4];
  float bo_v = 0.0f;
  float ysum[4] = {0, 0, 0, 0}, ysq[4] = {0, 0, 0, 0};
  int ybase[4] = {0, 0, 0, 0};
  if (w < 4) {
    int o = w * 16 + r;
    #pragma unroll
    for (int ks = 0; ks < 4; ks++) {
      bf16x8 f;
      #pragma unroll
      for (int e = 0; e < 8; e++)
        f[e] = (short)f2bf(Wo[(ks * 32 + kmap(e, q)) * TO + o]);
      wo[ks] = f;
    }
    bo_v = bo[o];
    #pragma unroll
    for (int i = 0; i < 4; i++) {
      int nn = q * 4 + i;
      ybase[i] = (s_b[nn] * TO + o) * (TT * TDD) + s_d[nn];
    }
  }
  __syncthreads();

  for (int t = 0; t < TT; t++) {
    const int p = t & 1, wp = p ^ 1;
    // issue x(t+3) loads (consumed 3 iterations from now)
    int tc = t + 3; if (tc >= TT) tc = TT - 1;
    float nx0 = xok[0] ? x[xbase[0] + tc * TDD] : 0.0f;
    float nx1 = xok[1] ? x[xbase[1] + tc * TDD] : 0.0f;

    // A-fragment reads (shared by gate-MFMA and y-MFMA)
    bf16x8 af[NKS];
    const ushort* Ab = ldsA[p];
    #pragma unroll
    for (int ks = 0; ks < NKS; ks++) {
      int B = (ks * 4 + q) * 16 + (r ^ q);
      af[ks] = *(const bf16x8*)&Ab[B * 8];
    }

    // gate pre-activations: 4 independent chains of 3 MFMAs (latency hiding)
    f32x4 a0a = {bz, bz, bz, bz}, a0b = {0, 0, 0, 0};
    f32x4 a1a = {bc, bc, bc, bc}, a1b = {0, 0, 0, 0};
    #pragma unroll
    for (int ks = 0; ks < NKS; ks += 2) {
      a0a = __builtin_amdgcn_mfma_f32_16x16x32_bf16(af[ks],     wf[0][ks],     a0a, 0, 0, 0);
      a0b = __builtin_amdgcn_mfma_f32_16x16x32_bf16(af[ks + 1], wf[0][ks + 1], a0b, 0, 0, 0);
      a1a = __builtin_amdgcn_mfma_f32_16x16x32_bf16(af[ks],     wf[1][ks],     a1a, 0, 0, 0);
      a1b = __builtin_amdgcn_mfma_f32_16x16x32_bf16(af[ks + 1], wf[1][ks + 1], a1b, 0, 0, 0);
    }

    // y_{t-1} = h_{t-1} @ Wo + bo on waves 0..3 (h-part frags = af[2..5])
    if (w < 4) {
      f32x4 yaa = {bo_v, bo_v, bo_v, bo_v}, yab = {0, 0, 0, 0};
      yaa = __builtin_amdgcn_mfma_f32_16x16x32_bf16(af[2], wo[0], yaa, 0, 0, 0);
      yab = __builtin_amdgcn_mfma_f32_16x16x32_bf16(af[3], wo[1], yab, 0, 0, 0);
      yaa = __builtin_amdgcn_mfma_f32_16x16x32_bf16(af[4], wo[2], yaa, 0, 0, 0);
      yab = __builtin_amdgcn_mfma_f32_16x16x32_bf16(af[5], wo[3], yab, 0, 0, 0);
      if (t >= 1) {
        int tm = t - 1;
        #pragma unroll
        for (int i = 0; i < 4; i++) {
          if (lok[i] && tm < llen[i]) {
            float v = yaa[i] + yab[i];
            yout[ybase[i] + tm * TDD] = v;
            ysum[i] += v; ysq[i] += v * v;
          }
        }
      }
    }

    // gates, fully in-register (lane owns unit ucol for rows nn=q*4+i)
    ushort hb[4];
    #pragma unroll
    for (int i = 0; i < 4; i++) {
      float a = a0a[i] + a0b[i];
      float b_ = a1a[i] + a1b[i];
      float z  = __builtin_amdgcn_rcpf(1.0f + __expf(-a));
      float hc = 1.0f - 2.0f * __builtin_amdgcn_rcpf(1.0f + __expf(2.0f * b_));
      float h  = z * hreg[i] + (1.0f - z) * hc;
      hreg[i] = (t < llen[i]) ? h : hreg[i];
      hb[i] = f2bf(hreg[i]);
    }
    // stage h_t and x_{t+1} into the other buffer
    ushort* Aw = ldsA[wp];
    #pragma unroll
    for (int i = 0; i < 4; i++) Aw[hwi[i]] = hb[i];
    Aw[xa[0]] = f2bf(wx0);
    Aw[xa[1]] = f2bf(wx1);
    wx0 = sx0; wx1 = sx1; sx0 = nx0; sx1 = nx1;

    __syncthreads();
  }

  // epilogue: y_{T-1} from h_{T-1} frags in buffer (TT & 1)
  if (w < 4) {
    const ushort* Ab = ldsA[TT & 1];
    bf16x8 ah[4];
    #pragma unroll
    for (int ks = 0; ks < 4; ks++) {
      int B = ((ks + 2) * 4 + q) * 16 + (r ^ q);
      ah[ks] = *(const bf16x8*)&Ab[B * 8];
    }
    f32x4 yaa = {bo_v, bo_v, bo_v, bo_v}, yab = {0, 0, 0, 0};
    yaa = __builtin_amdgcn_mfma_f32_16x16x32_bf16(ah[0], wo[0], yaa, 0, 0, 0);
    yab = __builtin_amdgcn_mfma_f32_16x16x32_bf16(ah[1], wo[1], yab, 0, 0, 0);
    yaa = __builtin_amdgcn_mfma_f32_16x16x32_bf16(ah[2], wo[2], yaa, 0, 0, 0);
    yab = __builtin_amdgcn_mfma_f32_16x16x32_bf16(ah[3], wo[3], yab, 0, 0, 0);
    const int tm = TT - 1;
    #pragma unroll
    for (int i = 0; i < 4; i++) {
      if (lok[i] && tm < llen[i]) {
        float v = yaa[i] + yab[i];
        yout[ybase[i] + tm * TDD] = v;
        ysum[i] += v; ysq[i] += v * v;
      }
    }
    int o = w * 16 + r;
    #pragma unroll
    for (int i = 0; i < 4; i++) {
      if (lok[i]) {
        atomicAdd(&ws[o * TDD + ld_[i]], ysum[i]);
        atomicAdd(&ws[ODCH + o * TDD + ld_[i]], ysq[i]);
      }
    }
  }
}

__global__ __launch_bounds__(256) void norm_kernel(
    const int* __restrict__ lengths, const float* __restrict__ gamma,
    const float* __restrict__ beta, const float* __restrict__ ws,
    float* __restrict__ out)
{
  __shared__ float s_cnt;
  if (threadIdx.x == 0) {
    int c = 0;
    #pragma unroll
    for (int b = 0; b < TB; b++) c += lengths[b];
    s_cnt = (float)c;
  }
  __syncthreads();
  int idx = blockIdx.x * 256 + threadIdx.x;   // TOTAL is an exact multiple of 256
  int d = idx % TDD;
  int rem = idx / TDD;
  int t = rem % TT;
  rem /= TT;
  int o = rem & 63;
  int b = rem >> 6;
  float res = 0.0f;
  if (t < lengths[b]) {
    int ch = o * TDD + d;
    float inv = 1.0f / s_cnt;
    float mean = ws[ch] * inv;
    float var = ws[ODCH + ch] * inv - mean * mean;
    res = (out[idx] - mean) * rsqrtf(var + 1e-5f) * gamma[ch] + beta[ch];
  }
  out[idx] = res;   // writes 0 at masked frames -> covers poison
}

extern "C" void kernel_launch(void* const* d_in, const int* in_sizes, int n_in,
                              void* d_out, int out_size, void* d_ws, size_t ws_size,
                              hipStream_t stream)
{
  const float* x       = (const float*)d_in[0];
  const int*   lengths = (const int*)d_in[1];
  const float* Wx      = (const float*)d_in[2];
  const float* Wh      = (const float*)d_in[3];
  const float* bias    = (const float*)d_in[4];
  const float* Wo      = (const float*)d_in[5];
  const float* bo      = (const float*)d_in[6];
  const float* gamma   = (const float*)d_in[7];
  const float* beta    = (const float*)d_in[8];
  float* out = (float*)d_out;
  float* ws  = (float*)d_ws;

  hipMemsetAsync(ws, 0, 2 * ODCH * sizeof(float), stream);
  hipLaunchKernelGGL(gru_kernel, dim3(NBLK), dim3(512), 0, stream,
                     x, lengths, Wx, Wh, bias, Wo, bo, out, ws);
  hipLaunchKernelGGL(norm_kernel, dim3(TOTAL / 256), dim3(256), 0, stream,
                     lengths, gamma, beta, ws, out);
}